// Round 2
// baseline (213.556 us; speedup 1.0000x reference)
//
#include <hip/hip_runtime.h>
#include <math.h>

// Problem constants (static config)
#define NB 1024     // batches
#define NS 64       // steps S
#define NT 63       // T = S-1
#define NV 192      // N = S*3 variables
#define BW 7        // band storage width: diag + 6 subdiagonals
#define NC 314      // constraint rows: 126 fw + 62 central + 126 bw
#define GSZ 1536    // per-batch ws floats: 1344 band/L + 192 rv/y
#define NG 16       // 1024/64 wave-groups

// ============================================================================
// Phase A: assemble banded AtA + rhs per batch (LDS), dump to ws in
// lane-transposed layout: ws[(g*GSZ + slot)*64 + (b&63)],  g = b>>6
// ============================================================================
__global__ __launch_bounds__(64, 1)
void ode_assemble(const float* __restrict__ coeffs,
                  const float* __restrict__ rhs,
                  const float* __restrict__ iv_rhs,
                  const float* __restrict__ steps,
                  float* __restrict__ ws)
{
    const int b    = blockIdx.x;
    const int lane = threadIdx.x;

    __shared__ float band[NV * BW];   // band[r*BW + d] = AtA[r][r-d]
    __shared__ float rv[NV];
    __shared__ float stp[NT + 1];

    for (int i = lane; i < NV * BW; i += 64) band[i] = 0.0f;
    if (lane < NT) stp[lane] = steps[b * NT + lane];
    __syncthreads();

    // block-diagonal AetAe + init-value reg + RHS (lane = step)
    {
        const int st = lane;
        const float c0 = coeffs[b * NV + st * 3 + 0];
        const float c1 = coeffs[b * NV + st * 3 + 1];
        const float c2 = coeffs[b * NV + st * 3 + 2];
        const float r  = rhs[b * NS + st];
        const float reg = (st < 2) ? 1.0f : 0.0f;
        atomicAdd(&band[(3 * st + 0) * BW + 0], c0 * c0 + reg);
        atomicAdd(&band[(3 * st + 1) * BW + 0], c1 * c1 + reg);
        atomicAdd(&band[(3 * st + 2) * BW + 0], c2 * c2);
        atomicAdd(&band[(3 * st + 1) * BW + 1], c1 * c0);
        atomicAdd(&band[(3 * st + 2) * BW + 1], c2 * c1);
        atomicAdd(&band[(3 * st + 2) * BW + 2], c2 * c0);
        float b0 = c0 * r, b1 = c1 * r, b2v = c2 * r;
        if (st < 2) {
            b0 += iv_rhs[b * 4 + st * 2 + 0];
            b1 += iv_rhs[b * 4 + st * 2 + 1];
        }
        rv[3 * st + 0] = b0;
        rv[3 * st + 1] = b1;
        rv[3 * st + 2] = b2v;
    }

    // constraint rows: accumulate A^T A into band via LDS atomics
    for (int t = lane; t < NC; t += 64) {
        int   cols[4];
        float vals[4];
        int   cnt;
        if (t < 126) {                      // forward Taylor
            const int st = t >> 1, i = t & 1;
            const float s = stp[st];
            if (i == 0) {
                cols[0] = 3 * st + 0; vals[0] = 1.0f;
                cols[1] = 3 * st + 1; vals[1] = s;
                cols[2] = 3 * st + 2; vals[2] = 0.5f * s * s;
                cols[3] = 3 * st + 3; vals[3] = -1.0f;
                cnt = 4;
            } else {
                cols[0] = 3 * st + 1; vals[0] = s;
                cols[1] = 3 * st + 2; vals[1] = s * s;
                cols[2] = 3 * st + 4; vals[2] = -s;
                cnt = 3;
            }
        } else if (t < 188) {               // central difference
            const int st = t - 126 + 1;
            const float cp = stp[st - 1] + stp[st];
            cols[0] = 3 * st - 2; vals[0] = -1.0f;
            cols[1] = 3 * st + 2; vals[1] = -cp;
            cols[2] = 3 * st + 4; vals[2] = 1.0f;
            cnt = 3;
        } else {                            // backward Taylor
            const int tt = t - 188;
            const int st = tt >> 1, i = tt & 1;
            const float s = stp[st];
            if (i == 0) {
                cols[0] = 3 * st + 0; vals[0] = -1.0f;
                cols[1] = 3 * st + 3; vals[1] = 1.0f;
                cols[2] = 3 * st + 4; vals[2] = -s;
                cols[3] = 3 * st + 5; vals[3] = 0.5f * s * s;
                cnt = 4;
            } else {
                cols[0] = 3 * st + 1; vals[0] = s;
                cols[1] = 3 * st + 4; vals[1] = -s;
                cols[2] = 3 * st + 5; vals[2] = s * s;
                cnt = 3;
            }
        }
        for (int a = 0; a < cnt; ++a)
            for (int b2 = 0; b2 <= a; ++b2)
                atomicAdd(&band[cols[a] * BW + (cols[a] - cols[b2])],
                          vals[a] * vals[b2]);
    }
    __syncthreads();

    // dump band + rv to workspace (lane-transposed layout, scattered 256B-stride
    // stores; writes are fire-and-forget)
    const int g = b >> 6, l = b & 63;
    float* __restrict__ wsg = ws + (size_t)g * GSZ * 64 + l;
    for (int i = lane; i < NV * BW; i += 64) wsg[(size_t)i * 64] = band[i];
    for (int i = lane; i < NV; i += 64)      wsg[(size_t)(NV * BW + i) * 64] = rv[i];
}

// ============================================================================
// Phase B: one THREAD per batch. Left-looking banded Cholesky (h=6) with the
// 6-column L-window entirely in registers (static indices), fused forward
// solve, in-place L/y store to ws, then streaming back-substitution.
// ws slot i for this thread: wsg[i*64]. All wave accesses coalesced (256B).
// ============================================================================
__global__ __launch_bounds__(64, 1)
void ode_factor_solve(float* __restrict__ ws, float* __restrict__ out)
{
    const int g = blockIdx.x;
    const int l = threadIdx.x;
    const int b = (g << 6) | l;
    float* __restrict__ wsg = ws + (size_t)g * GSZ * 64 + l;

#define LD(i)      wsg[(size_t)(i) * 64]
#define RVSLOT(j)  (NV * BW + (j))

    // W[p][k] = L[(j-p)+k][j-p], kept only for k >= p (diag never needed)
    float W11 = 0, W12 = 0, W13 = 0, W14 = 0, W15 = 0, W16 = 0;
    float W22 = 0, W23 = 0, W24 = 0, W25 = 0, W26 = 0;
    float W33 = 0, W34 = 0, W35 = 0, W36 = 0;
    float W44 = 0, W45 = 0, W46 = 0;
    float W55 = 0, W56 = 0;
    float W66 = 0;
    float y1 = 0, y2 = 0, y3 = 0, y4 = 0, y5 = 0, y6 = 0;

    // preload column 0: band[j+k][j] at slot (j+k)*7 + k
    float cb0 = LD(0);
    float cb1 = LD(8),  cb2 = LD(16), cb3 = LD(24);
    float cb4 = LD(32), cb5 = LD(40), cb6 = LD(48);
    float cr  = LD(RVSLOT(0));

    for (int j = 0; j < NV; ++j) {
        // ---- prefetch column j+1 (wave-uniform guards) ----
        float pb0 = 0, pb1 = 0, pb2 = 0, pb3 = 0, pb4 = 0, pb5 = 0, pb6 = 0, pr = 0;
        if (j + 1 < NV) {
            const int base = (j + 1) * BW;
            pb0 = LD(base);
            pb1 = LD(base + 8);
            if (j + 3 < NV) pb2 = LD(base + 16);
            if (j + 4 < NV) pb3 = LD(base + 24);
            if (j + 5 < NV) pb4 = LD(base + 32);
            if (j + 6 < NV) pb5 = LD(base + 40);
            if (j + 7 < NV) pb6 = LD(base + 48);
            pr = LD(RVSLOT(j + 1));
        }

        // ---- column j: s_k = band_k - sum_p W[p][p]*W[p][p+k] ----
        const float s0 = cb0 - (W11 * W11 + W22 * W22 + W33 * W33 +
                                W44 * W44 + W55 * W55 + W66 * W66);
        const float s1 = cb1 - (W11 * W12 + W22 * W23 + W33 * W34 +
                                W44 * W45 + W55 * W56);
        const float s2 = cb2 - (W11 * W13 + W22 * W24 + W33 * W35 + W44 * W46);
        const float s3 = cb3 - (W11 * W14 + W22 * W25 + W33 * W36);
        const float s4 = cb4 - (W11 * W15 + W22 * W26);
        const float s5 = cb5 - (W11 * W16);
        const float s6 = cb6;

        const float dinv = rsqrtf(s0);   // = 1 / L[j][j]
        const float yj = (cr - (W11 * y1 + W22 * y2 + W33 * y3 +
                                W44 * y4 + W55 * y5 + W66 * y6)) * dinv;

        const float n1 = (j + 1 < NV) ? s1 * dinv : 0.0f;
        const float n2 = (j + 2 < NV) ? s2 * dinv : 0.0f;
        const float n3 = (j + 3 < NV) ? s3 * dinv : 0.0f;
        const float n4 = (j + 4 < NV) ? s4 * dinv : 0.0f;
        const float n5 = (j + 5 < NV) ? s5 * dinv : 0.0f;
        const float n6 = (j + 6 < NV) ? s6 * dinv : 0.0f;

        // ---- store L column j in place of band; y in place of rv ----
        LD(j * BW) = dinv;                       // store 1/L[j][j]
        if (j + 1 < NV) LD((j + 1) * BW + 1) = n1;
        if (j + 2 < NV) LD((j + 2) * BW + 2) = n2;
        if (j + 3 < NV) LD((j + 3) * BW + 3) = n3;
        if (j + 4 < NV) LD((j + 4) * BW + 4) = n4;
        if (j + 5 < NV) LD((j + 5) * BW + 5) = n5;
        if (j + 6 < NV) LD((j + 6) * BW + 6) = n6;
        LD(RVSLOT(j)) = yj;

        // ---- shift window (p=6 down to p=1; all static regs) ----
        W66 = W56;
        W55 = W45; W56 = W46;
        W44 = W34; W45 = W35; W46 = W36;
        W33 = W23; W34 = W24; W35 = W25; W36 = W26;
        W22 = W12; W23 = W13; W24 = W14; W25 = W15; W26 = W16;
        W11 = n1;  W12 = n2;  W13 = n3;  W14 = n4;  W15 = n5;  W16 = n6;
        y6 = y5; y5 = y4; y4 = y3; y3 = y2; y2 = y1; y1 = yj;

        cb0 = pb0; cb1 = pb1; cb2 = pb2; cb3 = pb3;
        cb4 = pb4; cb5 = pb5; cb6 = pb6; cr = pr;
    }

    // ---- back-substitution: x[j] = (y[j] - sum_k L[j+k][j]*x[j+k]) / L[j][j]
    float x1 = 0, x2 = 0, x3 = 0, x4 = 0, x5 = 0, x6 = 0;

    // preload column NV-1 (no off-diagonals exist)
    float cdi = LD((NV - 1) * BW);
    float cL1 = 0, cL2 = 0, cL3 = 0, cL4 = 0, cL5 = 0, cL6 = 0;
    float cy  = LD(RVSLOT(NV - 1));

    for (int j = NV - 1; j >= 0; --j) {
        // ---- prefetch column j-1 ----
        float pdi = 0, pL1 = 0, pL2 = 0, pL3 = 0, pL4 = 0, pL5 = 0, pL6 = 0, py = 0;
        if (j - 1 >= 0) {
            const int jm = j - 1;
            pdi = LD(jm * BW);
            py  = LD(RVSLOT(jm));
            pL1 = LD((jm + 1) * BW + 1);
            if (jm + 2 < NV) pL2 = LD((jm + 2) * BW + 2);
            if (jm + 3 < NV) pL3 = LD((jm + 3) * BW + 3);
            if (jm + 4 < NV) pL4 = LD((jm + 4) * BW + 4);
            if (jm + 5 < NV) pL5 = LD((jm + 5) * BW + 5);
            if (jm + 6 < NV) pL6 = LD((jm + 6) * BW + 6);
        }

        // keep the freshest dependency (x1) last in the chain
        const float rest = (cL6 * x6 + cL5 * x5) + (cL4 * x4 + cL3 * x3) + cL2 * x2;
        const float xj = ((cy - rest) - cL1 * x1) * cdi;

        out[(size_t)b * NV + j] = xj;

        x6 = x5; x5 = x4; x4 = x3; x3 = x2; x2 = x1; x1 = xj;
        cdi = pdi; cL1 = pL1; cL2 = pL2; cL3 = pL3;
        cL4 = pL4; cL5 = pL5; cL6 = pL6; cy = py;
    }
#undef LD
#undef RVSLOT
}

// ============================================================================
// Fallback (round-1 kernel, passes): used only if ws_size < 6 MB
// ============================================================================
__global__ __launch_bounds__(64, 1)
void ode_banded_solve(const float* __restrict__ coeffs,
                      const float* __restrict__ rhs,
                      const float* __restrict__ iv_rhs,
                      const float* __restrict__ steps,
                      float* __restrict__ out)
{
    const int b    = blockIdx.x;
    const int lane = threadIdx.x;

    __shared__ float band[NV * BW];
    __shared__ float rv[NV];
    __shared__ float stp[NT + 1];

    for (int i = lane; i < NV * BW; i += 64) band[i] = 0.0f;
    if (lane < NT) stp[lane] = steps[b * NT + lane];
    __syncthreads();

    {
        const int st = lane;
        const float c0 = coeffs[b * NV + st * 3 + 0];
        const float c1 = coeffs[b * NV + st * 3 + 1];
        const float c2 = coeffs[b * NV + st * 3 + 2];
        const float r  = rhs[b * NS + st];
        const float reg = (st < 2) ? 1.0f : 0.0f;
        atomicAdd(&band[(3 * st + 0) * BW + 0], c0 * c0 + reg);
        atomicAdd(&band[(3 * st + 1) * BW + 0], c1 * c1 + reg);
        atomicAdd(&band[(3 * st + 2) * BW + 0], c2 * c2);
        atomicAdd(&band[(3 * st + 1) * BW + 1], c1 * c0);
        atomicAdd(&band[(3 * st + 2) * BW + 1], c2 * c1);
        atomicAdd(&band[(3 * st + 2) * BW + 2], c2 * c0);
        float b0 = c0 * r, b1 = c1 * r, b2v = c2 * r;
        if (st < 2) {
            b0 += iv_rhs[b * 4 + st * 2 + 0];
            b1 += iv_rhs[b * 4 + st * 2 + 1];
        }
        rv[3 * st + 0] = b0;
        rv[3 * st + 1] = b1;
        rv[3 * st + 2] = b2v;
    }

    for (int t = lane; t < NC; t += 64) {
        int   cols[4];
        float vals[4];
        int   cnt;
        if (t < 126) {
            const int st = t >> 1, i = t & 1;
            const float s = stp[st];
            if (i == 0) {
                cols[0] = 3 * st + 0; vals[0] = 1.0f;
                cols[1] = 3 * st + 1; vals[1] = s;
                cols[2] = 3 * st + 2; vals[2] = 0.5f * s * s;
                cols[3] = 3 * st + 3; vals[3] = -1.0f;
                cnt = 4;
            } else {
                cols[0] = 3 * st + 1; vals[0] = s;
                cols[1] = 3 * st + 2; vals[1] = s * s;
                cols[2] = 3 * st + 4; vals[2] = -s;
                cnt = 3;
            }
        } else if (t < 188) {
            const int st = t - 126 + 1;
            const float cp = stp[st - 1] + stp[st];
            cols[0] = 3 * st - 2; vals[0] = -1.0f;
            cols[1] = 3 * st + 2; vals[1] = -cp;
            cols[2] = 3 * st + 4; vals[2] = 1.0f;
            cnt = 3;
        } else {
            const int tt = t - 188;
            const int st = tt >> 1, i = tt & 1;
            const float s = stp[st];
            if (i == 0) {
                cols[0] = 3 * st + 0; vals[0] = -1.0f;
                cols[1] = 3 * st + 3; vals[1] = 1.0f;
                cols[2] = 3 * st + 4; vals[2] = -s;
                cols[3] = 3 * st + 5; vals[3] = 0.5f * s * s;
                cnt = 4;
            } else {
                cols[0] = 3 * st + 1; vals[0] = s;
                cols[1] = 3 * st + 4; vals[1] = -s;
                cols[2] = 3 * st + 5; vals[2] = s * s;
                cnt = 3;
            }
        }
        for (int a = 0; a < cnt; ++a)
            for (int b2 = 0; b2 <= a; ++b2)
                atomicAdd(&band[cols[a] * BW + (cols[a] - cols[b2])],
                          vals[a] * vals[b2]);
    }
    __syncthreads();

    int pa = 0, pb = 0;
    {
        int idx = 0;
        for (int aa = 1; aa <= 6; ++aa)
            for (int bb = 1; bb <= aa; ++bb) {
                if (idx == lane) { pa = aa; pb = bb; }
                ++idx;
            }
    }
    const int sk = lane - 20;

    for (int j = 0; j < NV; ++j) {
        const int m = (NV - 1 - j < 6) ? (NV - 1 - j) : 6;
        const float diag = band[j * BW];
        const float d    = sqrtf(diag);
        const float dinv = 1.0f / d;

        const bool doU = (lane < 21) && (pa <= m);
        const bool doS = (lane >= 21) && (lane <= 26) && (sk <= m);
        float ca = 0.0f, cb = 0.0f, cs = 0.0f;
        if (doU) { ca = band[(j + pa) * BW + pa]; cb = band[(j + pb) * BW + pb]; }
        if (doS) { cs = band[(j + sk) * BW + sk]; }
        __syncthreads();

        if (lane == 0) band[j * BW] = d;
        if (doU) band[(j + pa) * BW + (pa - pb)] -= ca * cb * (dinv * dinv);
        if (doS) band[(j + sk) * BW + sk] = cs * dinv;
        __syncthreads();
    }

    for (int j = 0; j < NV; ++j) {
        const int m = (NV - 1 - j < 6) ? (NV - 1 - j) : 6;
        const float yj = rv[j] / band[j * BW];
        const bool doK = (lane >= 1) && (lane <= m);
        float sub = 0.0f, rj = 0.0f;
        if (doK) { sub = band[(j + lane) * BW + lane] * yj; rj = rv[j + lane]; }
        __syncthreads();
        if (lane == 0) rv[j] = yj;
        if (doK) rv[j + lane] = rj - sub;
        __syncthreads();
    }

    for (int j = NV - 1; j >= 0; --j) {
        const int m = (j < 6) ? j : 6;
        const float xj = rv[j] / band[j * BW];
        const bool doK = (lane >= 1) && (lane <= m);
        float sub = 0.0f, rj = 0.0f;
        if (doK) { sub = band[j * BW + lane] * xj; rj = rv[j - lane]; }
        __syncthreads();
        if (lane == 0) rv[j] = xj;
        if (doK) rv[j - lane] = rj - sub;
        __syncthreads();
    }

    for (int i = lane; i < NV; i += 64)
        out[b * NV + i] = rv[i];
}

extern "C" void kernel_launch(void* const* d_in, const int* in_sizes, int n_in,
                              void* d_out, int out_size, void* d_ws, size_t ws_size,
                              hipStream_t stream)
{
    const float* coeffs = (const float*)d_in[0];   // 1024*64*3
    const float* rhs    = (const float*)d_in[1];   // 1024*64
    const float* iv_rhs = (const float*)d_in[2];   // 1024*2*2
    const float* steps  = (const float*)d_in[3];   // 1024*63
    float* out = (float*)d_out;                    // 1024*192

    const size_t need = (size_t)NG * GSZ * 64 * sizeof(float);   // 6 MB
    if (ws_size >= need) {
        ode_assemble<<<dim3(NB), dim3(64), 0, stream>>>(coeffs, rhs, iv_rhs, steps,
                                                        (float*)d_ws);
        ode_factor_solve<<<dim3(NG), dim3(64), 0, stream>>>((float*)d_ws, out);
    } else {
        ode_banded_solve<<<dim3(NB), dim3(64), 0, stream>>>(coeffs, rhs, iv_rhs,
                                                            steps, out);
    }
}

// Round 3
// 65.419 us; speedup vs baseline: 3.2644x; 3.2644x over previous
//
#include <hip/hip_runtime.h>
#include <math.h>

// Problem constants (static config)
#define NB 1024     // batches
#define NS 64       // steps S
#define NT 63       // T = S-1
#define NV 192      // N = S*3 variables
#define BW 7        // band half-width+1 (fallback kernel)
#define NC 314      // constraint rows (fallback kernel)
#define GSZ (NV*8)  // per-batch ws floats: 8 per column (dinv, L1..L6, y)
#define NG 16       // 1024/64 wave-groups

// ============================================================================
// Fused kernel: one THREAD per batch.
//  - Band columns of AtA computed ON THE FLY from steps/coeffs (closed form,
//    verified against the atomic-assembly build of rounds 1-2).
//  - Left-looking banded Cholesky (h=6), 6-column register window, fused
//    forward solve. Loop 1 only WRITES ws (L columns + y, 8 floats/col,
//    lane-transposed coalesced layout).
//  - Loop 2 (back-substitution) only READS ws, writes out.
// No load-store aliasing inside either loop -> no per-iteration waitcnt drain.
// ============================================================================
__global__ __launch_bounds__(64, 1)
void ode_fused(const float* __restrict__ coeffs,   // (B, S, 1, 1, 3)
               const float* __restrict__ rhs,      // (B, S, 1)
               const float* __restrict__ iv_rhs,   // (B, 2, 1, 2)
               const float* __restrict__ steps,    // (B, T)
               float* __restrict__ ws,
               float* __restrict__ out)            // (B, S, 1, 3)
{
    const int g = blockIdx.x;
    const int l = threadIdx.x;
    const int b = (g << 6) | l;
    float* __restrict__ wsg = ws + (size_t)g * GSZ * 64 + l;

#define SL(i) wsg[(size_t)(i) * 64]

    // ---- Cholesky window: W[p][k] = L[(j-p)+k][j-p], k >= p ----
    float W11 = 0, W12 = 0, W13 = 0, W14 = 0, W15 = 0, W16 = 0;
    float W22 = 0, W23 = 0, W24 = 0, W25 = 0, W26 = 0;
    float W33 = 0, W34 = 0, W35 = 0, W36 = 0;
    float W44 = 0, W45 = 0, W46 = 0;
    float W55 = 0, W56 = 0;
    float W66 = 0;
    float y1 = 0, y2 = 0, y3 = 0, y4 = 0, y5 = 0, y6 = 0;

#define CHOL_COL(j, b0, b1, b2, b3, b4, b5, b6, rvv)                           \
    {                                                                          \
        const float t0 = (b0) - (W11*W11 + W22*W22 + W33*W33 +                 \
                                 W44*W44 + W55*W55 + W66*W66);                 \
        const float dinv = rsqrtf(t0);                                         \
        const float u1 = (b1) - (W11*W12 + W22*W23 + W33*W34 +                 \
                                 W44*W45 + W55*W56);                           \
        const float u2 = (b2) - (W11*W13 + W22*W24 + W33*W35 + W44*W46);       \
        const float u3 = (b3) - (W11*W14 + W22*W25 + W33*W36);                 \
        const float u4 = (b4) - (W11*W15 + W22*W26);                           \
        const float u5 = (b5) - (W11*W16);                                     \
        const float u6 = (b6);                                                 \
        const float yj = ((rvv) - (W11*y1 + W22*y2 + W33*y3 +                  \
                                   W44*y4 + W55*y5 + W66*y6)) * dinv;          \
        const float n1 = u1*dinv, n2 = u2*dinv, n3 = u3*dinv;                  \
        const float n4 = u4*dinv, n5 = u5*dinv, n6 = u6*dinv;                  \
        SL((j)*8 + 0) = dinv; SL((j)*8 + 1) = n1;  SL((j)*8 + 2) = n2;         \
        SL((j)*8 + 3) = n3;   SL((j)*8 + 4) = n4;  SL((j)*8 + 5) = n5;         \
        SL((j)*8 + 6) = n6;   SL((j)*8 + 7) = yj;                              \
        W66 = W56;                                                             \
        W55 = W45; W56 = W46;                                                  \
        W44 = W34; W45 = W35; W46 = W36;                                       \
        W33 = W23; W34 = W24; W35 = W25; W36 = W26;                            \
        W22 = W12; W23 = W13; W24 = W14; W25 = W15; W26 = W16;                 \
        W11 = n1;  W12 = n2;  W13 = n3;  W14 = n4;  W15 = n5;  W16 = n6;       \
        y6 = y5; y5 = y4; y4 = y3; y3 = y2; y2 = y1; y1 = yj;                  \
    }

    // ---- initial-value rhs additions (steps 0,1; orders 0,1) ----
    const float iv00 = iv_rhs[(size_t)b*4 + 0];
    const float iv01 = iv_rhs[(size_t)b*4 + 1];
    const float iv10 = iv_rhs[(size_t)b*4 + 2];
    const float iv11 = iv_rhs[(size_t)b*4 + 3];

    // ---- streamed inputs: p = s_{t-1}, s = s_t, sn = s_{t+1} ----
    float p  = 0.f;
    float s  = steps[(size_t)b*NT + 0];
    float sn = steps[(size_t)b*NT + 1];
    float c0 = coeffs[(size_t)b*NV + 0];
    float c1 = coeffs[(size_t)b*NV + 1];
    float c2 = coeffs[(size_t)b*NV + 2];
    float r  = rhs[(size_t)b*NS + 0];

    for (int t = 0; t < NS; ++t) {
        // prefetch next step's inputs (consumed next iteration)
        float nc0 = 0, nc1 = 0, nc2 = 0, nr = 0, ns2 = 0;
        if (t + 1 < NS) {
            const size_t cb = (size_t)b*NV + (size_t)(t + 1)*3;
            nc0 = coeffs[cb + 0];
            nc1 = coeffs[cb + 1];
            nc2 = coeffs[cb + 2];
            nr  = rhs[(size_t)b*NS + (t + 1)];
            if (t + 2 < NT) ns2 = steps[(size_t)b*NT + (t + 2)];
        }

        // wave-uniform boundary masks
        const float mS  = (t < NS - 1) ? 1.f : 0.f;              // fw/bw(t) exist
        const float mP  = (t >= 1)     ? 1.f : 0.f;              // fw/bw(t-1) exist
        const float mCN = (t < NS - 2) ? 1.f : 0.f;              // CE(t+1) exists
        const float mC0 = (t >= 1 && t < NS - 1) ? 1.f : 0.f;    // CE(t) exists
        const float rg  = (t < 2) ? 1.f : 0.f;                   // IV regularization
        const float ivA = (t == 0) ? iv00 : ((t == 1) ? iv10 : 0.f);
        const float ivB = (t == 0) ? iv01 : ((t == 1) ? iv11 : 0.f);

        // band columns of AtA for step t (closed form; s=0 at t=63, p=0 at t=0
        // auto-gate most boundary terms)
        const float s2 = s*s, s3 = s2*s, p2 = p*p, p3 = p2*p;
        const float gt = p + s;                                   // cp of CE(t)

        const float A0 = c0*c0 + rg + 2.f*(mS + mP);
        const float A1 = c0*c1 + s - p;
        const float A2 = c0*c2 + 0.5f*(s2 + p2);
        const float A3 = -2.f*mS;
        const float A4 = s;
        const float A5 = -0.5f*s2;

        const float B0 = c1*c1 + 3.f*(s2 + p2) + mCN + 1.f;
        const float B1 = c1*c2 + 1.5f*(s3 - p3);
        const float B2 = -s;
        const float B3 = -2.f*s2;
        const float B4 = s3 + (s + sn)*mCN;                       // cp of CE(t+1)
        const float B6 = -mCN;

        const float Cv0 = c2*c2 + 1.25f*(s2*s2 + p2*p2) + gt*gt*mC0;
        const float Cv1 = -0.5f*s2;
        const float Cv2 = -s3 - gt*mC0;

        const float rv0 = c0*r + ivA;
        const float rv1 = c1*r + ivB;
        const float rv2 = c2*r;

        const int j0 = 3*t;
        CHOL_COL(j0 + 0, A0,  A1,  A2,  A3,  A4,  A5,  0.f, rv0);
        CHOL_COL(j0 + 1, B0,  B1,  B2,  B3,  B4,  0.f, B6,  rv1);
        CHOL_COL(j0 + 2, Cv0, Cv1, Cv2, 0.f, 0.f, 0.f, 0.f, rv2);

        p = s; s = sn; sn = ns2;
        c0 = nc0; c1 = nc1; c2 = nc2; r = nr;
    }

    // ---- back-substitution: x[j] = (y[j] - sum_k L[j+k][j]*x[j+k]) * dinv[j]
#define DECL8(P) float P##d = 0, P##1 = 0, P##2 = 0, P##3 = 0,                 \
                       P##4 = 0, P##5 = 0, P##6 = 0, P##y = 0;
#define LOAD8(P, j) { const size_t o8 = (size_t)(j)*8;                         \
        P##d = SL(o8 + 0); P##1 = SL(o8 + 1); P##2 = SL(o8 + 2);               \
        P##3 = SL(o8 + 3); P##4 = SL(o8 + 4); P##5 = SL(o8 + 5);               \
        P##6 = SL(o8 + 6); P##y = SL(o8 + 7); }
#define COPY8(D, S8) { D##d = S8##d; D##1 = S8##1; D##2 = S8##2;               \
        D##3 = S8##3; D##4 = S8##4; D##5 = S8##5; D##6 = S8##6; D##y = S8##y; }
#define BSUB(P, j) {                                                           \
        const float rest = (P##6*x6 + P##5*x5) + (P##4*x4 + P##3*x3) + P##2*x2;\
        const float xr = ((P##y - rest) - P##1*x1) * P##d;                     \
        out[(size_t)b*NV + (j)] = xr;                                          \
        x6 = x5; x5 = x4; x4 = x3; x3 = x2; x2 = x1; x1 = xr; }

    float x1 = 0, x2 = 0, x3 = 0, x4 = 0, x5 = 0, x6 = 0;
    DECL8(cC) DECL8(cB) DECL8(cA)
    DECL8(nC) DECL8(nB) DECL8(nA)

    LOAD8(cC, NV - 1)
    LOAD8(cB, NV - 2)
    LOAD8(cA, NV - 3)

    for (int t = NS - 1; t >= 0; --t) {
        if (t > 0) {            // prefetch step t-1's three columns
            const int jb = 3*(t - 1);
            LOAD8(nC, jb + 2)
            LOAD8(nB, jb + 1)
            LOAD8(nA, jb + 0)
        }
        const int j0 = 3*t;
        BSUB(cC, j0 + 2)
        BSUB(cB, j0 + 1)
        BSUB(cA, j0 + 0)
        COPY8(cC, nC) COPY8(cB, nB) COPY8(cA, nA)
    }

#undef SL
#undef CHOL_COL
#undef DECL8
#undef LOAD8
#undef COPY8
#undef BSUB
}

// ============================================================================
// Fallback (round-1 kernel, known-pass): used only if ws_size < 6.3 MB
// ============================================================================
__global__ __launch_bounds__(64, 1)
void ode_banded_solve(const float* __restrict__ coeffs,
                      const float* __restrict__ rhs,
                      const float* __restrict__ iv_rhs,
                      const float* __restrict__ steps,
                      float* __restrict__ out)
{
    const int b    = blockIdx.x;
    const int lane = threadIdx.x;

    __shared__ float band[NV * BW];
    __shared__ float rv[NV];
    __shared__ float stp[NT + 1];

    for (int i = lane; i < NV * BW; i += 64) band[i] = 0.0f;
    if (lane < NT) stp[lane] = steps[b * NT + lane];
    __syncthreads();

    {
        const int st = lane;
        const float c0 = coeffs[b * NV + st * 3 + 0];
        const float c1 = coeffs[b * NV + st * 3 + 1];
        const float c2 = coeffs[b * NV + st * 3 + 2];
        const float r  = rhs[b * NS + st];
        const float reg = (st < 2) ? 1.0f : 0.0f;
        atomicAdd(&band[(3 * st + 0) * BW + 0], c0 * c0 + reg);
        atomicAdd(&band[(3 * st + 1) * BW + 0], c1 * c1 + reg);
        atomicAdd(&band[(3 * st + 2) * BW + 0], c2 * c2);
        atomicAdd(&band[(3 * st + 1) * BW + 1], c1 * c0);
        atomicAdd(&band[(3 * st + 2) * BW + 1], c2 * c1);
        atomicAdd(&band[(3 * st + 2) * BW + 2], c2 * c0);
        float b0 = c0 * r, b1 = c1 * r, b2v = c2 * r;
        if (st < 2) {
            b0 += iv_rhs[b * 4 + st * 2 + 0];
            b1 += iv_rhs[b * 4 + st * 2 + 1];
        }
        rv[3 * st + 0] = b0;
        rv[3 * st + 1] = b1;
        rv[3 * st + 2] = b2v;
    }

    for (int t = lane; t < NC; t += 64) {
        int   cols[4];
        float vals[4];
        int   cnt;
        if (t < 126) {
            const int st = t >> 1, i = t & 1;
            const float s = stp[st];
            if (i == 0) {
                cols[0] = 3 * st + 0; vals[0] = 1.0f;
                cols[1] = 3 * st + 1; vals[1] = s;
                cols[2] = 3 * st + 2; vals[2] = 0.5f * s * s;
                cols[3] = 3 * st + 3; vals[3] = -1.0f;
                cnt = 4;
            } else {
                cols[0] = 3 * st + 1; vals[0] = s;
                cols[1] = 3 * st + 2; vals[1] = s * s;
                cols[2] = 3 * st + 4; vals[2] = -s;
                cnt = 3;
            }
        } else if (t < 188) {
            const int st = t - 126 + 1;
            const float cp = stp[st - 1] + stp[st];
            cols[0] = 3 * st - 2; vals[0] = -1.0f;
            cols[1] = 3 * st + 2; vals[1] = -cp;
            cols[2] = 3 * st + 4; vals[2] = 1.0f;
            cnt = 3;
        } else {
            const int tt = t - 188;
            const int st = tt >> 1, i = tt & 1;
            const float s = stp[st];
            if (i == 0) {
                cols[0] = 3 * st + 0; vals[0] = -1.0f;
                cols[1] = 3 * st + 3; vals[1] = 1.0f;
                cols[2] = 3 * st + 4; vals[2] = -s;
                cols[3] = 3 * st + 5; vals[3] = 0.5f * s * s;
                cnt = 4;
            } else {
                cols[0] = 3 * st + 1; vals[0] = s;
                cols[1] = 3 * st + 4; vals[1] = -s;
                cols[2] = 3 * st + 5; vals[2] = s * s;
                cnt = 3;
            }
        }
        for (int a = 0; a < cnt; ++a)
            for (int b2 = 0; b2 <= a; ++b2)
                atomicAdd(&band[cols[a] * BW + (cols[a] - cols[b2])],
                          vals[a] * vals[b2]);
    }
    __syncthreads();

    int pa = 0, pb = 0;
    {
        int idx = 0;
        for (int aa = 1; aa <= 6; ++aa)
            for (int bb = 1; bb <= aa; ++bb) {
                if (idx == lane) { pa = aa; pb = bb; }
                ++idx;
            }
    }
    const int sk = lane - 20;

    for (int j = 0; j < NV; ++j) {
        const int m = (NV - 1 - j < 6) ? (NV - 1 - j) : 6;
        const float diag = band[j * BW];
        const float d    = sqrtf(diag);
        const float dinv = 1.0f / d;

        const bool doU = (lane < 21) && (pa <= m);
        const bool doS = (lane >= 21) && (lane <= 26) && (sk <= m);
        float ca = 0.0f, cb = 0.0f, cs = 0.0f;
        if (doU) { ca = band[(j + pa) * BW + pa]; cb = band[(j + pb) * BW + pb]; }
        if (doS) { cs = band[(j + sk) * BW + sk]; }
        __syncthreads();

        if (lane == 0) band[j * BW] = d;
        if (doU) band[(j + pa) * BW + (pa - pb)] -= ca * cb * (dinv * dinv);
        if (doS) band[(j + sk) * BW + sk] = cs * dinv;
        __syncthreads();
    }

    for (int j = 0; j < NV; ++j) {
        const int m = (NV - 1 - j < 6) ? (NV - 1 - j) : 6;
        const float yj = rv[j] / band[j * BW];
        const bool doK = (lane >= 1) && (lane <= m);
        float sub = 0.0f, rj = 0.0f;
        if (doK) { sub = band[(j + lane) * BW + lane] * yj; rj = rv[j + lane]; }
        __syncthreads();
        if (lane == 0) rv[j] = yj;
        if (doK) rv[j + lane] = rj - sub;
        __syncthreads();
    }

    for (int j = NV - 1; j >= 0; --j) {
        const int m = (j < 6) ? j : 6;
        const float xj = rv[j] / band[j * BW];
        const bool doK = (lane >= 1) && (lane <= m);
        float sub = 0.0f, rj = 0.0f;
        if (doK) { sub = band[j * BW + lane] * xj; rj = rv[j - lane]; }
        __syncthreads();
        if (lane == 0) rv[j] = xj;
        if (doK) rv[j - lane] = rj - sub;
        __syncthreads();
    }

    for (int i = lane; i < NV; i += 64)
        out[b * NV + i] = rv[i];
}

extern "C" void kernel_launch(void* const* d_in, const int* in_sizes, int n_in,
                              void* d_out, int out_size, void* d_ws, size_t ws_size,
                              hipStream_t stream)
{
    const float* coeffs = (const float*)d_in[0];   // 1024*64*3
    const float* rhs    = (const float*)d_in[1];   // 1024*64
    const float* iv_rhs = (const float*)d_in[2];   // 1024*2*2
    const float* steps  = (const float*)d_in[3];   // 1024*63
    float* out = (float*)d_out;                    // 1024*192

    const size_t need = (size_t)NG * GSZ * 64 * sizeof(float);   // ~6.3 MB
    if (ws_size >= need) {
        ode_fused<<<dim3(NG), dim3(64), 0, stream>>>(coeffs, rhs, iv_rhs, steps,
                                                     (float*)d_ws, out);
    } else {
        ode_banded_solve<<<dim3(NB), dim3(64), 0, stream>>>(coeffs, rhs, iv_rhs,
                                                            steps, out);
    }
}